// Round 1
// baseline (1393.198 us; speedup 1.0000x reference)
//
#include <hip/hip_runtime.h>

#define T_TOK 8192
#define DDIM  2048
#define NEXP  8
#define IDIM  1408
#define SIDIM 2816
#define MAXSLOTS 17408  // 16384 + 8*128 worst-case padding

typedef short  v8s  __attribute__((ext_vector_type(8)));
typedef __bf16 v8bf __attribute__((ext_vector_type(8)));
typedef float  v4f  __attribute__((ext_vector_type(4)));

__device__ __forceinline__ unsigned short f2bf_bits(float f){
  union { float fv; unsigned u; } v; v.fv = f;
  unsigned r = v.u + 0x7fffu + ((v.u >> 16) & 1u);  // RNE
  return (unsigned short)(r >> 16);
}

__device__ __forceinline__ void gld16(const void* g, void* l){
  __builtin_amdgcn_global_load_lds(
      (const __attribute__((address_space(1))) unsigned int*)g,
      (__attribute__((address_space(3))) unsigned int*)l, 16, 0, 0);
}

__device__ __forceinline__ v4f mfma16(v8s a, v8s b, v4f c){
  return __builtin_amdgcn_mfma_f32_16x16x32_bf16(
      __builtin_bit_cast(v8bf, a), __builtin_bit_cast(v8bf, b), c, 0, 0, 0);
}

// ---------------- small kernels ----------------

__global__ __launch_bounds__(256) void route_init_k(int* rows, float* roww, int* counts){
  int i = blockIdx.x*256 + threadIdx.x;
  if (i < MAXSLOTS){ rows[i] = 0; roww[i] = 0.f; }
  if (i < NEXP) counts[i] = 0;
}

__global__ __launch_bounds__(256) void cvt_bf16_k(const float4* __restrict__ s,
                                                  ushort4* __restrict__ d, int n4){
  int i = blockIdx.x*256 + threadIdx.x;
  int stride = gridDim.x*256;
  for (; i < n4; i += stride){
    float4 v = s[i];
    d[i] = make_ushort4(f2bf_bits(v.x), f2bf_bits(v.y), f2bf_bits(v.z), f2bf_bits(v.w));
  }
}

// gate (fp32) + x -> bf16 cast. One wave per token.
__global__ __launch_bounds__(256) void gate_cast_k(const float* __restrict__ x,
    const float* __restrict__ gw, unsigned short* __restrict__ xbf,
    int* __restrict__ tidx, float* __restrict__ tw, int* __restrict__ counts){
  int t = threadIdx.x, w = t>>6, lane = t&63;
  int token = blockIdx.x*4 + w;
  const float* xr = x + (size_t)token*DDIM;
  float acc[NEXP];
  #pragma unroll
  for (int e=0;e<NEXP;++e) acc[e]=0.f;
  #pragma unroll
  for (int i=0;i<8;++i){
    int d = i*256 + lane*4;
    float4 xv = *(const float4*)(xr + d);
    *(ushort4*)(xbf + (size_t)token*DDIM + d) =
        make_ushort4(f2bf_bits(xv.x), f2bf_bits(xv.y), f2bf_bits(xv.z), f2bf_bits(xv.w));
    #pragma unroll
    for (int e=0;e<NEXP;++e){
      float4 g = *(const float4*)(gw + e*DDIM + d);
      acc[e] += xv.x*g.x + xv.y*g.y + xv.z*g.z + xv.w*g.w;
    }
  }
  #pragma unroll
  for (int off=32; off; off>>=1){
    #pragma unroll
    for (int e=0;e<NEXP;++e) acc[e] += __shfl_xor(acc[e], off);
  }
  if (lane == 0){
    float mx = acc[0];
    #pragma unroll
    for (int e=1;e<NEXP;++e) mx = fmaxf(mx, acc[e]);
    float p[NEXP], s = 0.f;
    #pragma unroll
    for (int e=0;e<NEXP;++e){ p[e] = __expf(acc[e]-mx); s += p[e]; }
    float inv = 1.f/s;
    #pragma unroll
    for (int e=0;e<NEXP;++e) p[e] *= inv;
    int i0 = 0;
    #pragma unroll
    for (int e=1;e<NEXP;++e) if (p[e] > p[i0]) i0 = e;
    int i1 = (i0==0) ? 1 : 0;
    #pragma unroll
    for (int e=0;e<NEXP;++e) if (e!=i0 && e!=i1 && p[e] > p[i1]) i1 = e;
    tidx[token*2+0] = i0; tidx[token*2+1] = i1;
    tw[token*2+0] = p[i0]; tw[token*2+1] = p[i1];
    atomicAdd(&counts[i0], 1); atomicAdd(&counts[i1], 1);
  }
}

__global__ void route_offsets_k(const int* counts, int* pad_off, int* pad_cnt, int* fill){
  if (threadIdx.x == 0){
    int o = 0;
    for (int e=0;e<NEXP;++e){
      pad_off[e] = o;
      int pc = (counts[e] + 127) & ~127;
      pad_cnt[e] = pc;
      o += pc;
    }
  }
  if (threadIdx.x < NEXP) fill[threadIdx.x] = 0;
}

__global__ __launch_bounds__(256) void scatter_k(const int* __restrict__ tidx,
    const float* __restrict__ tw, const int* __restrict__ pad_off,
    int* __restrict__ fill, int* __restrict__ rows, float* __restrict__ roww){
  int t = blockIdx.x*256 + threadIdx.x;
  int lane = threadIdx.x & 63;
  #pragma unroll
  for (int k=0;k<2;++k){
    int e = tidx[t*2+k];
    float wgt = tw[t*2+k];
    for (int ee=0; ee<NEXP; ++ee){
      unsigned long long m = __ballot(e == ee);
      if (m){
        int leader = __ffsll((unsigned long long)m) - 1;
        int base = 0;
        if (lane == leader) base = atomicAdd(&fill[ee], __popcll(m));
        base = __shfl(base, leader);
        if (e == ee){
          int rank = __popcll(m & ((1ull<<lane)-1ull));
          int pos = pad_off[ee] + base + rank;
          rows[pos] = t; roww[pos] = wgt;
        }
      }
    }
  }
}

// ---------------- GEMM kernels (128x128 tile, BK=32, 4 waves) ----------------

// H = silu(A@B0^T) * (A@B1^T), A rows optionally gathered. Output bf16.
template<bool GATHER>
__global__ __launch_bounds__(256,2) void gemm_dual_silu_k(
    const unsigned short* __restrict__ Abase,
    const unsigned short* __restrict__ B0base,
    const unsigned short* __restrict__ B1base,
    unsigned short* __restrict__ Hbase,
    const int* __restrict__ rows,
    const int* __restrict__ pad_off, const int* __restrict__ pad_cnt,
    int K, int N)
{
  int e = blockIdx.z;
  int off = 0, mcnt = T_TOK;
  if (GATHER){ off = pad_off[e]; mcnt = pad_cnt[e]; }
  int brow = blockIdx.x * 128;
  if (brow >= mcnt) return;
  int bcol = blockIdx.y * 128;

  const unsigned short* B0 = B0base + (size_t)e * (size_t)N * (size_t)K;
  const unsigned short* B1 = B1base + (size_t)e * (size_t)N * (size_t)K;
  unsigned short* H = Hbase + (size_t)off * (size_t)N;

  __shared__ unsigned short As [128*32];
  __shared__ unsigned short Bs0[128*32];
  __shared__ unsigned short Bs1[128*32];

  int t = threadIdx.x, w = t>>6, lane = t&63;
  int srow = lane>>2, scol = (lane&3)*8;

  const unsigned short *ag[2], *b0g[2], *b1g[2];
  #pragma unroll
  for (int j=0;j<2;++j){
    int r = brow + j*64 + w*16 + srow;
    int tok = GATHER ? rows[off + r] : r;
    ag[j] = Abase + (size_t)tok*(size_t)K + scol;
    int rb = bcol + j*64 + w*16 + srow;
    b0g[j] = B0 + (size_t)rb*(size_t)K + scol;
    b1g[j] = B1 + (size_t)rb*(size_t)K + scol;
  }

  v4f acc0[4][4], acc1[4][4];
  #pragma unroll
  for (int m=0;m<4;++m)
    #pragma unroll
    for (int n=0;n<4;++n){
      acc0[m][n] = (v4f){0.f,0.f,0.f,0.f};
      acc1[m][n] = (v4f){0.f,0.f,0.f,0.f};
    }

  int fr = lane & 15, fq = lane >> 4;
  int wr = (w>>1)*64, wc = (w&1)*64;

  for (int k0=0; k0<K; k0+=32){
    __syncthreads();
    #pragma unroll
    for (int j=0;j<2;++j){
      int lo = (j*256 + w*64)*16;
      gld16(ag[j]  + k0, (char*)As  + lo);
      gld16(b0g[j] + k0, (char*)Bs0 + lo);
      gld16(b1g[j] + k0, (char*)Bs1 + lo);
    }
    __syncthreads();
    v8s af[4];
    #pragma unroll
    for (int m=0;m<4;++m) af[m] = *(const v8s*)(As + (wr + m*16 + fr)*32 + fq*8);
    #pragma unroll
    for (int n=0;n<4;++n){
      v8s b0f = *(const v8s*)(Bs0 + (wc + n*16 + fr)*32 + fq*8);
      v8s b1f = *(const v8s*)(Bs1 + (wc + n*16 + fr)*32 + fq*8);
      #pragma unroll
      for (int m=0;m<4;++m){
        acc0[m][n] = mfma16(af[m], b0f, acc0[m][n]);
        acc1[m][n] = mfma16(af[m], b1f, acc1[m][n]);
      }
    }
  }

  #pragma unroll
  for (int m=0;m<4;++m){
    #pragma unroll
    for (int n=0;n<4;++n){
      #pragma unroll
      for (int r=0;r<4;++r){
        int row = brow + wr + m*16 + fq*4 + r;
        int col = bcol + wc + n*16 + fr;
        float a = acc0[m][n][r];
        float b = acc1[m][n][r];
        float h = a * b / (1.f + __expf(-a));
        H[(size_t)row*(size_t)N + col] = f2bf_bits(h);
      }
    }
  }
}

// out = A@B^T (N fixed = DDIM). ATOMIC: out[tok] += w*val; else plain store.
template<bool ATOMIC>
__global__ __launch_bounds__(256,2) void gemm_out_k(
    const unsigned short* __restrict__ Abase,
    const unsigned short* __restrict__ Bbase,
    float* __restrict__ out,
    const int* __restrict__ rows, const float* __restrict__ roww,
    const int* __restrict__ pad_off, const int* __restrict__ pad_cnt,
    int K)
{
  int e = blockIdx.z;
  int off = 0, mcnt = T_TOK;
  if (ATOMIC){ off = pad_off[e]; mcnt = pad_cnt[e]; }
  int brow = blockIdx.x * 128;
  if (brow >= mcnt) return;
  int bcol = blockIdx.y * 128;

  const unsigned short* A  = Abase + (size_t)off * (size_t)K;
  const unsigned short* Bm = Bbase + (size_t)e * (size_t)DDIM * (size_t)K;

  __shared__ unsigned short As[128*32];
  __shared__ unsigned short Bs[128*32];

  int t = threadIdx.x, w = t>>6, lane = t&63;
  int srow = lane>>2, scol = (lane&3)*8;

  const unsigned short *ag[2], *bg[2];
  #pragma unroll
  for (int j=0;j<2;++j){
    ag[j] = A  + (size_t)(brow + j*64 + w*16 + srow)*(size_t)K + scol;
    bg[j] = Bm + (size_t)(bcol + j*64 + w*16 + srow)*(size_t)K + scol;
  }

  v4f acc[4][4];
  #pragma unroll
  for (int m=0;m<4;++m)
    #pragma unroll
    for (int n=0;n<4;++n) acc[m][n] = (v4f){0.f,0.f,0.f,0.f};

  int fr = lane & 15, fq = lane >> 4;
  int wr = (w>>1)*64, wc = (w&1)*64;

  for (int k0=0; k0<K; k0+=32){
    __syncthreads();
    #pragma unroll
    for (int j=0;j<2;++j){
      int lo = (j*256 + w*64)*16;
      gld16(ag[j] + k0, (char*)As + lo);
      gld16(bg[j] + k0, (char*)Bs + lo);
    }
    __syncthreads();
    v8s af[4];
    #pragma unroll
    for (int m=0;m<4;++m) af[m] = *(const v8s*)(As + (wr + m*16 + fr)*32 + fq*8);
    #pragma unroll
    for (int n=0;n<4;++n){
      v8s bf = *(const v8s*)(Bs + (wc + n*16 + fr)*32 + fq*8);
      #pragma unroll
      for (int m=0;m<4;++m) acc[m][n] = mfma16(af[m], bf, acc[m][n]);
    }
  }

  #pragma unroll
  for (int m=0;m<4;++m){
    #pragma unroll
    for (int r=0;r<4;++r){
      int slot = brow + wr + m*16 + fq*4 + r;
      int tok = slot; float wgt = 1.f;
      if (ATOMIC){ tok = rows[off+slot]; wgt = roww[off+slot]; }
      #pragma unroll
      for (int n=0;n<4;++n){
        int col = bcol + wc + n*16 + fr;
        float v = acc[m][n][r];
        if (ATOMIC) atomicAdd(out + (size_t)tok*DDIM + col, wgt*v);
        else        out[(size_t)slot*DDIM + col] = v;
      }
    }
  }
}

// ---------------- launcher ----------------

extern "C" void kernel_launch(void* const* d_in, const int* in_sizes, int n_in,
                              void* d_out, int out_size, void* d_ws, size_t ws_size,
                              hipStream_t stream)
{
  const float* x   = (const float*)d_in[0];
  const float* gw  = (const float*)d_in[1];
  const float* w1  = (const float*)d_in[2];
  const float* w2  = (const float*)d_in[3];
  const float* w3  = (const float*)d_in[4];
  const float* sw1 = (const float*)d_in[5];
  const float* sw2 = (const float*)d_in[6];
  const float* sw3 = (const float*)d_in[7];
  float* out = (float*)d_out;

  char* p = (char*)d_ws;
  auto alloc = [&](size_t bytes)->char*{
    char* r = p; p += (bytes + 255) & ~(size_t)255; return r;
  };
  const size_t NW  = (size_t)NEXP*IDIM*DDIM;   // routed weight elems
  const size_t NSW = (size_t)SIDIM*DDIM;       // shared weight elems

  unsigned short* xbf  = (unsigned short*)alloc((size_t)T_TOK*DDIM*2);
  unsigned short* w1b  = (unsigned short*)alloc(NW*2);
  unsigned short* w3b  = (unsigned short*)alloc(NW*2);
  unsigned short* w2b  = (unsigned short*)alloc(NW*2);
  unsigned short* sw1b = (unsigned short*)alloc(NSW*2);
  unsigned short* sw3b = (unsigned short*)alloc(NSW*2);
  unsigned short* sw2b = (unsigned short*)alloc(NSW*2);
  // shared between Hs [8192][2816] and routed H [17408][1408] (time-disjoint)
  unsigned short* Hbuf = (unsigned short*)alloc((size_t)MAXSLOTS*IDIM*2);
  int*   tidx    = (int*)  alloc((size_t)T_TOK*2*4);
  float* tw      = (float*)alloc((size_t)T_TOK*2*4);
  int*   rows    = (int*)  alloc((size_t)MAXSLOTS*4);
  float* roww    = (float*)alloc((size_t)MAXSLOTS*4);
  int*   counts  = (int*)  alloc(NEXP*4);
  int*   pad_off = (int*)  alloc(NEXP*4);
  int*   pad_cnt = (int*)  alloc(NEXP*4);
  int*   fill    = (int*)  alloc(NEXP*4);

  // 1. init routing state
  route_init_k<<<(MAXSLOTS+255)/256, 256, 0, stream>>>(rows, roww, counts);

  // 2. weight conversions fp32 -> bf16
  cvt_bf16_k<<<2048, 256, 0, stream>>>((const float4*)w1,  (ushort4*)w1b,  (int)(NW/4));
  cvt_bf16_k<<<2048, 256, 0, stream>>>((const float4*)w3,  (ushort4*)w3b,  (int)(NW/4));
  cvt_bf16_k<<<2048, 256, 0, stream>>>((const float4*)w2,  (ushort4*)w2b,  (int)(NW/4));
  cvt_bf16_k<<<1024, 256, 0, stream>>>((const float4*)sw1, (ushort4*)sw1b, (int)(NSW/4));
  cvt_bf16_k<<<1024, 256, 0, stream>>>((const float4*)sw3, (ushort4*)sw3b, (int)(NSW/4));
  cvt_bf16_k<<<1024, 256, 0, stream>>>((const float4*)sw2, (ushort4*)sw2b, (int)(NSW/4));

  // 3. gate + cast
  gate_cast_k<<<T_TOK/4, 256, 0, stream>>>(x, gw, xbf, tidx, tw, counts);

  // 4. routing offsets + scatter
  route_offsets_k<<<1, 64, 0, stream>>>(counts, pad_off, pad_cnt, fill);
  scatter_k<<<T_TOK/256, 256, 0, stream>>>(tidx, tw, pad_off, fill, rows, roww);

  // 5. shared expert: Hs = silu(x@sw1^T)*(x@sw3^T); out = Hs@sw2^T (store)
  gemm_dual_silu_k<false><<<dim3(T_TOK/128, SIDIM/128, 1), 256, 0, stream>>>(
      xbf, sw1b, sw3b, Hbuf, nullptr, nullptr, nullptr, DDIM, SIDIM);
  gemm_out_k<false><<<dim3(T_TOK/128, DDIM/128, 1), 256, 0, stream>>>(
      Hbuf, sw2b, out, nullptr, nullptr, nullptr, nullptr, SIDIM);

  // 6. routed experts: H = silu(xg@w1^T)*(xg@w3^T); out += w * (H@w2^T) (atomic)
  gemm_dual_silu_k<true><<<dim3(T_TOK/128, IDIM/128, NEXP), 256, 0, stream>>>(
      xbf, w1b, w3b, Hbuf, rows, pad_off, pad_cnt, DDIM, IDIM);
  gemm_out_k<true><<<dim3(T_TOK/128, DDIM/128, NEXP), 256, 0, stream>>>(
      Hbuf, w2b, out, rows, roww, pad_off, pad_cnt, IDIM);
}